// Round 1
// baseline (18083.942 us; speedup 1.0000x reference)
//
#include <hip/hip_runtime.h>
#include <hip/hip_bf16.h>
#include <stdint.h>

typedef unsigned int uint;
typedef unsigned long long u64;

#define T_STEPS 128
#define BQ 16
#define HID 512
#define XROW 580        // 576 padded (bank-conflict-free b128 reads)
#define HROW 516        // 512 padded
#define WROW 516
#define MROW 68         // 64 padded
#define NSLOT 1024
#define MD 64
#define VOCAB 32000
#define NWG 128
#define BETA 1.000001f
#define EPSN 1e-8f

__device__ __forceinline__ float sigm(float x){ return 1.f/(1.f+expf(-x)); }

// pack (score, slot) so that u64 max == (max value, min slot on ties) — matches lax.top_k
__device__ __forceinline__ u64 packsc(float v, int slot){
  uint u = __float_as_uint(v);
  u = (u & 0x80000000u) ? ~u : (u | 0x80000000u);
  return ((u64)u << 10) | (u64)(1023 - slot);
}
__device__ __forceinline__ float unpackval(u64 p){
  uint u = (uint)(p >> 10);
  uint bits = (u & 0x80000000u) ? (u & 0x7fffffffu) : ~u;
  return __uint_as_float(bits);
}
__device__ __forceinline__ int unpackslot(u64 p){ return 1023 - (int)(p & 1023u); }

// grid barrier: all NWG workgroups co-resident (grid 128 <= 256 CUs)
__device__ __forceinline__ void gbar(uint* bar, uint& ls){
  __syncthreads();
  __threadfence();   // agent-scope release of this WG's writes
  if (threadIdx.x == 0){
    ls++;
    uint v = __hip_atomic_fetch_add(&bar[0], 1u, __ATOMIC_ACQ_REL, __HIP_MEMORY_SCOPE_AGENT);
    if (v == NWG-1u){
      __hip_atomic_store(&bar[0], 0u, __ATOMIC_RELAXED, __HIP_MEMORY_SCOPE_AGENT);
      __hip_atomic_store(&bar[1], ls, __ATOMIC_RELEASE, __HIP_MEMORY_SCOPE_AGENT);
    } else {
      while (__hip_atomic_load(&bar[1], __ATOMIC_ACQUIRE, __HIP_MEMORY_SCOPE_AGENT) != ls)
        __builtin_amdgcn_s_sleep(2);
    }
  }
  __syncthreads();
  __threadfence();   // invalidate stale L1/L2 before consuming others' writes
}

// ---------------- phase 0a: embedding gather ----------------
__global__ __launch_bounds__(256) void prep_emb(const float* __restrict__ E,
                                                const int* __restrict__ seq,
                                                float* __restrict__ EMB){
  int m = blockIdx.x;              // m = t*16 + b
  int t = m >> 4, b = m & 15;
  int x = seq[b*T_STEPS + t];
  EMB[(size_t)m*256 + threadIdx.x] = E[(size_t)x*256 + threadIdx.x];
}

// ---------------- phase 0b: G_emb[m][p] = EMB[m] . W_ih[r(p)][0:256] + b_ih[r]+b_hh[r] ----
// p packing: p = u*4+g, r = g*512+u
__global__ __launch_bounds__(256) void gemm_emb(const float* __restrict__ A,
                                                const float* __restrict__ W_ih,
                                                const float* __restrict__ b_ih,
                                                const float* __restrict__ b_hh,
                                                float* __restrict__ C){
  __shared__ __align__(16) float As[16*68];
  __shared__ __align__(16) float Bs[16*68];
  int mt = blockIdx.x & 31, nt = blockIdx.x >> 5;
  int m0 = mt*64, n0 = nt*64;
  int tx = threadIdx.x & 15, ty = threadIdx.x >> 4;
  float acc[4][4] = {};
  for (int k0 = 0; k0 < 256; k0 += 16){
    int mm = threadIdx.x >> 2, kq = (threadIdx.x & 3)*4;
    float4 a = *(const float4*)(A + (size_t)(m0+mm)*256 + k0 + kq);
    As[(kq+0)*68+mm]=a.x; As[(kq+1)*68+mm]=a.y; As[(kq+2)*68+mm]=a.z; As[(kq+3)*68+mm]=a.w;
    int pp = n0 + mm;
    int r = (pp & 3)*512 + (pp >> 2);
    float4 bv = *(const float4*)(W_ih + (size_t)r*320 + k0 + kq);
    Bs[(kq+0)*68+mm]=bv.x; Bs[(kq+1)*68+mm]=bv.y; Bs[(kq+2)*68+mm]=bv.z; Bs[(kq+3)*68+mm]=bv.w;
    __syncthreads();
    #pragma unroll
    for (int kk = 0; kk < 16; ++kk){
      float4 av = *(const float4*)(As + kk*68 + ty*4);
      float4 bb = *(const float4*)(Bs + kk*68 + tx*4);
      float aa[4] = {av.x,av.y,av.z,av.w};
      float bv2[4] = {bb.x,bb.y,bb.z,bb.w};
      #pragma unroll
      for (int i = 0; i < 4; ++i)
        #pragma unroll
        for (int j = 0; j < 4; ++j)
          acc[i][j] = fmaf(aa[i], bv2[j], acc[i][j]);
    }
    __syncthreads();
  }
  #pragma unroll
  for (int i = 0; i < 4; ++i){
    int m = m0 + ty*4 + i;
    #pragma unroll
    for (int j = 0; j < 4; ++j){
      int pp = n0 + tx*4 + j;
      int r = (pp & 3)*512 + (pp >> 2);
      C[(size_t)m*2048 + pp] = acc[i][j] + b_ih[r] + b_hh[r];
    }
  }
}

// ---------------- the sequential recurrence ----------------
__global__ __launch_bounds__(256) void recurrent_kernel(
    const float* __restrict__ W_hh, const float* __restrict__ W_ih,
    const float* __restrict__ W_rk, const float* __restrict__ b_rk,
    const float* __restrict__ W_wk, const float* __restrict__ b_wk,
    const float* __restrict__ W_wv, const float* __restrict__ b_wv,
    const float* __restrict__ W_er, const float* __restrict__ b_er,
    const float* __restrict__ G_emb, float* __restrict__ H_all,
    float* __restrict__ mem, float* __restrict__ projbuf,
    float* __restrict__ rv_head, u64* __restrict__ cand,
    u64* __restrict__ wlist, uint* __restrict__ bar)
{
  __shared__ __align__(16) float smem[12448];
  const int tid = threadIdx.x;
  const int wg  = blockIdx.x;
  uint ls = 0;
  float c_reg = 0.f;

  const int p1_b = tid >> 4, p1_col = tid & 15;
  const int pcol = wg*16 + p1_col;                 // packed gate index
  const int rrow = (pcol & 3)*512 + (pcol >> 2);   // original W row

  #pragma clang loop unroll(disable)
  for (int t = 0; t < T_STEPS; ++t){
    // ======== P1: gates + LSTM (WG owns units wg*4..wg*4+3) ========
    {
      float* xs = smem;                  // [16][XROW]
      float* gl = smem + BQ*XROW;        // [16][16]
      if (t > 0){
        const float4* hsrc = (const float4*)(H_all + (size_t)(t-1)*BQ*HID);
        for (int i = tid; i < BQ*HID/4; i += 256){
          int b = i >> 7, q = i & 127;
          *(float4*)(xs + b*XROW + q*4) = hsrc[i];
        }
        for (int i = tid; i < BQ*MD/4; i += 256){
          int b = i >> 4, dq = i & 15;
          const float4* rh = (const float4*)(rv_head + (size_t)b*4*MD);
          float4 r0 = rh[dq], r1 = rh[16+dq], r2 = rh[32+dq], r3 = rh[48+dq];
          float4 o;
          o.x = 0.25f*(r0.x+r1.x+r2.x+r3.x);
          o.y = 0.25f*(r0.y+r1.y+r2.y+r3.y);
          o.z = 0.25f*(r0.z+r1.z+r2.z+r3.z);
          o.w = 0.25f*(r0.w+r1.w+r2.w+r3.w);
          *(float4*)(xs + b*XROW + 512 + dq*4) = o;
        }
      } else {
        for (int i = tid; i < BQ*XROW; i += 256) xs[i] = 0.f;
      }
      __syncthreads();
      {
        float acc = G_emb[(size_t)(t*BQ + p1_b)*2048 + pcol];
        const float4* wh = (const float4*)(W_hh + (size_t)rrow*HID);
        const float4* xv = (const float4*)(xs + p1_b*XROW);
        #pragma unroll 8
        for (int k = 0; k < 128; ++k){
          float4 w = wh[k], x = xv[k];
          acc = fmaf(w.x,x.x,acc); acc = fmaf(w.y,x.y,acc);
          acc = fmaf(w.z,x.z,acc); acc = fmaf(w.w,x.w,acc);
        }
        const float4* wi = (const float4*)(W_ih + (size_t)rrow*320 + 256);
        const float4* xr = (const float4*)(xs + p1_b*XROW + 512);
        #pragma unroll
        for (int k = 0; k < 16; ++k){
          float4 w = wi[k], x = xr[k];
          acc = fmaf(w.x,x.x,acc); acc = fmaf(w.y,x.y,acc);
          acc = fmaf(w.z,x.z,acc); acc = fmaf(w.w,x.w,acc);
        }
        gl[p1_b*16 + p1_col] = acc;
      }
      __syncthreads();
      if (p1_col < 4){
        float gi = gl[p1_b*16 + p1_col*4 + 0];
        float gf = gl[p1_b*16 + p1_col*4 + 1];
        float gg = gl[p1_b*16 + p1_col*4 + 2];
        float go = gl[p1_b*16 + p1_col*4 + 3];
        c_reg = sigm(gf)*c_reg + sigm(gi)*tanhf(gg);
        float h = sigm(go)*tanhf(c_reg);
        H_all[(size_t)(t*BQ + p1_b)*HID + wg*4 + p1_col] = h;
      }
    }
    gbar(bar, ls);   // B1: h_t visible

    // ======== P2: projections rk|wk|wv|er (WG owns 8 output dims) ========
    {
      float* hs = smem;                 // [16][HROW]
      float* Ws = smem + BQ*HROW;       // [8][WROW]
      const int msel = wg >> 5;
      const int col0 = (wg & 31)*8;
      const float* Wm = (msel==0)? W_rk : (msel==1)? W_wk : (msel==2)? W_wv : W_er;
      const float* bm = (msel==0)? b_rk : (msel==1)? b_wk : (msel==2)? b_wv : b_er;
      const float4* hsrc = (const float4*)(H_all + (size_t)t*BQ*HID);
      for (int i = tid; i < BQ*HID/4; i += 256){
        int b = i >> 7, q = i & 127;
        *(float4*)(hs + b*HROW + q*4) = hsrc[i];
      }
      for (int i = tid; i < 8*HID; i += 256){
        int k = i >> 3, j = i & 7;
        Ws[j*WROW + k] = Wm[(size_t)k*256 + col0 + j];
      }
      __syncthreads();
      int b = tid >> 4, o2 = (tid & 15) >> 1, half = tid & 1;
      const float4* wp = (const float4*)(Ws + o2*WROW + half*256);
      const float4* xp = (const float4*)(hs + b*HROW + half*256);
      float acc = 0.f;
      #pragma unroll 8
      for (int k = 0; k < 64; ++k){
        float4 w = wp[k], x = xp[k];
        acc = fmaf(w.x,x.x,acc); acc = fmaf(w.y,x.y,acc);
        acc = fmaf(w.z,x.z,acc); acc = fmaf(w.w,x.w,acc);
      }
      float other = __shfl_xor(acc, 1);
      if (half == 0){
        float v = acc + other + bm[col0 + o2];
        if (msel == 3) v = sigm(v);
        projbuf[(size_t)(t&1)*BQ*1024 + (size_t)b*1024 + msel*256 + col0 + o2] = v;
      }
    }
    gbar(bar, ls);   // B2: keys + er/wv visible

    // ======== P3: deferred mem update + norms + scores + local top8 ========
    {
      const int bb = wg >> 3, rg = wg & 7, s0 = rg*128;
      float* mem_s  = smem;                    // [128][MROW]
      float* key_s  = smem + 128*MROW;         // 512
      float* nrm_s  = key_s + 512;             // 128
      float* knrm_s = nrm_s + 128;             // 8
      float* sc_s   = knrm_s + 8;              // [8][128]
      float* mslice = mem + ((size_t)bb*NSLOT + s0)*MD;
      const int par = t & 1, parp = (t & 1) ^ 1;
      if (t == 0){
        for (int i = tid; i < 128*MD; i += 256) mslice[i] = 1e-6f;
      } else if (tid < 64){
        const float* erp = projbuf + (size_t)parp*BQ*1024 + (size_t)bb*1024 + 768;
        const float* wvp = projbuf + (size_t)parp*BQ*1024 + (size_t)bb*1024 + 512;
        int d = tid;
        // all erases first (keep = product over heads), then all adds
        for (int h = 0; h < 4; ++h)
          for (int j = 0; j < 8; ++j){
            u64 e = wlist[(bb*4+h)*8 + j];
            int sl = (int)(e & 0xffffffffu);
            if (sl >= s0 && sl < s0+128){
              float w = __uint_as_float((uint)(e >> 32));
              mem[((size_t)bb*NSLOT + sl)*MD + d] *= (1.f - w*erp[h*MD + d]);
            }
          }
        for (int h = 0; h < 4; ++h)
          for (int j = 0; j < 8; ++j){
            u64 e = wlist[(bb*4+h)*8 + j];
            int sl = (int)(e & 0xffffffffu);
            if (sl >= s0 && sl < s0+128){
              float w = __uint_as_float((uint)(e >> 32));
              mem[((size_t)bb*NSLOT + sl)*MD + d] += w*wvp[h*MD + d];
            }
          }
      }
      __syncthreads();
      // stage memory slice + keys to LDS
      for (int i = tid; i < 128*MD/4; i += 256){
        int s = i >> 4, dq = i & 15;
        *(float4*)(mem_s + s*MROW + dq*4) = ((const float4*)mslice)[i];
      }
      for (int i = tid; i < 512; i += 256)
        key_s[i] = projbuf[(size_t)par*BQ*1024 + (size_t)bb*1024 + i];
      __syncthreads();
      {
        int s = tid >> 1, half = tid & 1;
        const float4* mp = (const float4*)(mem_s + s*MROW + half*32);
        float sum = 0.f;
        #pragma unroll
        for (int q = 0; q < 8; ++q){
          float4 v = mp[q];
          sum = fmaf(v.x,v.x,sum); sum = fmaf(v.y,v.y,sum);
          sum = fmaf(v.z,v.z,sum); sum = fmaf(v.w,v.w,sum);
        }
        sum += __shfl_xor(sum, 1);
        if (half == 0) nrm_s[s] = sqrtf(sum) + EPSN;
      }
      if (tid < 8){
        const float4* kp = (const float4*)(key_s + tid*MD);
        float sum = 0.f;
        #pragma unroll
        for (int q = 0; q < 16; ++q){
          float4 v = kp[q];
          sum = fmaf(v.x,v.x,sum); sum = fmaf(v.y,v.y,sum);
          sum = fmaf(v.z,v.z,sum); sum = fmaf(v.w,v.w,sum);
        }
        knrm_s[tid] = sqrtf(sum) + EPSN;
      }
      __syncthreads();
      {
        int s = tid >> 1, kh = tid & 1;
        const float4* mp = (const float4*)(mem_s + s*MROW);
        float rnm = 1.f / nrm_s[s];
        #pragma unroll
        for (int kk = 0; kk < 4; ++kk){
          int key = kh*4 + kk;
          const float4* kp = (const float4*)(key_s + key*MD);
          float acc = 0.f;
          #pragma unroll
          for (int q = 0; q < 16; ++q){
            float4 m = mp[q], k4 = kp[q];
            acc = fmaf(m.x,k4.x,acc); acc = fmaf(m.y,k4.y,acc);
            acc = fmaf(m.z,k4.z,acc); acc = fmaf(m.w,k4.w,acc);
          }
          sc_s[key*128 + s] = BETA * acc * rnm / knrm_s[key];
        }
      }
      __syncthreads();
      {
        int wid = tid >> 6, lane = tid & 63;
        for (int kk = 0; kk < 2; ++kk){
          int key = wid*2 + kk;
          u64 p0 = packsc(sc_s[key*128 + lane],      s0 + lane);
          u64 p1 = packsc(sc_s[key*128 + 64 + lane], s0 + 64 + lane);
          #pragma unroll
          for (int r = 0; r < 8; ++r){
            u64 m = p0 > p1 ? p0 : p1;
            #pragma unroll
            for (int o = 32; o; o >>= 1){ u64 q = __shfl_xor(m, o); if (q > m) m = q; }
            if (p0 == m) p0 = 0; else if (p1 == m) p1 = 0;
            if (lane == 0) cand[(((size_t)bb*8 + key)*8 + rg)*8 + r] = m;
          }
        }
      }
    }
    gbar(bar, ls);   // B3: candidates visible

    // ======== P4: merge top8, softmax, read_vec, write-lists (one WG per b) ========
    if (wg < BQ){
      const int bb = wg;
      int wid = tid >> 6, lane = tid & 63;
      for (int kk = 0; kk < 2; ++kk){
        int key = wid*2 + kk;
        u64 pv = cand[(((size_t)bb*8 + key)*8 + (lane >> 3))*8 + (lane & 7)];
        u64 sel = 0;
        #pragma unroll
        for (int r = 0; r < 8; ++r){
          u64 m = pv;
          #pragma unroll
          for (int o = 32; o; o >>= 1){ u64 q = __shfl_xor(m, o); if (q > m) m = q; }
          if (pv == m) pv = 0;
          if (lane == r) sel = m;
        }
        float val = unpackval(sel);
        int slot = unpackslot(sel);
        float vmax = __shfl(val, 0);
        float e = (lane < 8) ? expf(val - vmax) : 0.f;
        float ssum = e;
        #pragma unroll
        for (int o = 32; o; o >>= 1) ssum += __shfl_xor(ssum, o);
        float w = e / ssum;
        if (key < 4){
          float acc = 0.f;
          #pragma unroll
          for (int i = 0; i < 8; ++i){
            float wi = __shfl(w, i);
            int sl = __shfl(slot, i);
            acc = fmaf(wi, mem[((size_t)bb*NSLOT + sl)*MD + lane], acc);
          }
          rv_head[((size_t)bb*4 + key)*MD + lane] = acc;
        } else if (lane < 8){
          wlist[((size_t)bb*4 + (key-4))*8 + lane] =
              ((u64)__float_as_uint(w) << 32) | (u64)(uint)slot;
        }
      }
    }
    gbar(bar, ls);   // B4: rv + write lists visible
  }
}

// ---------------- phase B: logits = H_all[2048,512] @ W_out[512,32000] + b_out ----------------
__global__ __launch_bounds__(256) void gemm_out(const float* __restrict__ A,
                                                const float* __restrict__ Bmat,
                                                const float* __restrict__ bias,
                                                float* __restrict__ C){
  __shared__ __align__(16) float As[16*132];
  __shared__ __align__(16) float Bs[16*64];
  int mt = blockIdx.x & 15, nt = blockIdx.x >> 4;
  int m0 = mt*128, n0 = nt*64;
  int tx = threadIdx.x & 15, ty = threadIdx.x >> 4;
  float acc[8][4] = {};
  for (int k0 = 0; k0 < 512; k0 += 16){
    int mm = threadIdx.x >> 1, kq = (threadIdx.x & 1)*8;
    float4 a0 = *(const float4*)(A + (size_t)(m0+mm)*512 + k0 + kq);
    float4 a1 = *(const float4*)(A + (size_t)(m0+mm)*512 + k0 + kq + 4);
    As[(kq+0)*132+mm]=a0.x; As[(kq+1)*132+mm]=a0.y; As[(kq+2)*132+mm]=a0.z; As[(kq+3)*132+mm]=a0.w;
    As[(kq+4)*132+mm]=a1.x; As[(kq+5)*132+mm]=a1.y; As[(kq+6)*132+mm]=a1.z; As[(kq+7)*132+mm]=a1.w;
    int kk2 = threadIdx.x >> 4, nq = (threadIdx.x & 15)*4;
    *(float4*)(Bs + kk2*64 + nq) = *(const float4*)(Bmat + (size_t)(k0+kk2)*VOCAB + n0 + nq);
    __syncthreads();
    #pragma unroll
    for (int kk = 0; kk < 16; ++kk){
      float4 x0 = *(const float4*)(As + kk*132 + ty*8);
      float4 x1 = *(const float4*)(As + kk*132 + ty*8 + 4);
      float4 bv = *(const float4*)(Bs + kk*64 + tx*4);
      float aa[8] = {x0.x,x0.y,x0.z,x0.w,x1.x,x1.y,x1.z,x1.w};
      float bb[4] = {bv.x,bv.y,bv.z,bv.w};
      #pragma unroll
      for (int i = 0; i < 8; ++i)
        #pragma unroll
        for (int j = 0; j < 4; ++j)
          acc[i][j] = fmaf(aa[i], bb[j], acc[i][j]);
    }
    __syncthreads();
  }
  #pragma unroll
  for (int i = 0; i < 8; ++i){
    int m = m0 + ty*8 + i;
    int bq = m & 15, tt = m >> 4;
    float* crow = C + ((size_t)bq*T_STEPS + tt)*VOCAB + n0 + tx*4;
    #pragma unroll
    for (int j = 0; j < 4; ++j) crow[j] = acc[i][j] + bias[n0 + tx*4 + j];
  }
}

extern "C" void kernel_launch(void* const* d_in, const int* in_sizes, int n_in,
                              void* d_out, int out_size, void* d_ws, size_t ws_size,
                              hipStream_t stream){
  const int*   seq   = (const int*)d_in[0];
  const float* E     = (const float*)d_in[1];
  const float* W_ih  = (const float*)d_in[2];
  const float* W_hh  = (const float*)d_in[3];
  const float* b_ih  = (const float*)d_in[4];
  const float* b_hh  = (const float*)d_in[5];
  const float* W_out = (const float*)d_in[6];
  const float* b_out = (const float*)d_in[7];
  const float* W_rk  = (const float*)d_in[8];
  const float* b_rk  = (const float*)d_in[9];
  const float* W_wk  = (const float*)d_in[10];
  const float* b_wk  = (const float*)d_in[11];
  const float* W_wv  = (const float*)d_in[12];
  const float* b_wv  = (const float*)d_in[13];
  const float* W_er  = (const float*)d_in[14];
  const float* b_er  = (const float*)d_in[15];
  float* out = (float*)d_out;
  (void)in_sizes; (void)n_in; (void)out_size; (void)ws_size;

  char* ws = (char*)d_ws;
  size_t off = 0;
  auto alloc = [&](size_t bytes) -> void* {
    off = (off + 255) & ~(size_t)255;
    void* p = ws + off;
    off += bytes;
    return p;
  };
  float* EMB     = (float*)alloc((size_t)2048*256*4);
  float* G_emb   = (float*)alloc((size_t)2048*2048*4);
  float* H_all   = (float*)alloc((size_t)2048*512*4);
  float* memb    = (float*)alloc((size_t)16*1024*64*4);
  float* projbuf = (float*)alloc((size_t)2*16*1024*4);
  float* rv_head = (float*)alloc((size_t)16*4*64*4);
  u64*   cand    = (u64*)alloc((size_t)16*8*8*8*8);
  u64*   wlist   = (u64*)alloc((size_t)16*4*8*8);
  uint*  bar     = (uint*)alloc(256);

  hipMemsetAsync(bar, 0, 256, stream);
  prep_emb<<<2048, 256, 0, stream>>>(E, seq, EMB);
  gemm_emb<<<1024, 256, 0, stream>>>(EMB, W_ih, b_ih, b_hh, G_emb);
  recurrent_kernel<<<NWG, 256, 0, stream>>>(W_hh, W_ih, W_rk, b_rk, W_wk, b_wk,
                                            W_wv, b_wv, W_er, b_er,
                                            G_emb, H_all, memb, projbuf, rv_head,
                                            cand, wlist, bar);
  gemm_out<<<16*500, 256, 0, stream>>>(H_all, W_out, b_out, out);
}

// Round 2
// 7330.314 us; speedup vs baseline: 2.4670x; 2.4670x over previous
//
#include <hip/hip_runtime.h>
#include <hip/hip_bf16.h>
#include <stdint.h>

typedef unsigned int uint;
typedef unsigned long long u64;

#define T_STEPS 128
#define BQ 16
#define HID 512
#define XROW 580        // 576 padded
#define WROW 516
#define NSLOT 1024
#define MD 64
#define VOCAB 32000
#define NWG 128
#define BETA 1.000001f
#define EPSN 1e-8f

// LDS layout (floats): persistent mem slice + norms + proj weights, then scratch union
#define OFF_NRM 8704        // mem_s[128*68] ends here
#define OFF_WS  8832        // nrm[128] ends here
#define OFF_SCR 12960       // Ws[8*516] ends here; scratch = 9536 floats
#define SMEM_F  22496       // 89984 bytes

// batched agent-coherent (bypass L1/L2) loads; one waitcnt per batch (rule #18: sched_barrier after)
#define AL4(dst, p) asm volatile("global_load_dwordx4 %0, %1, off sc0 sc1" : "=v"(dst) : "v"(p))
#define ALF(dst, p) asm volatile("global_load_dword %0, %1, off sc0 sc1" : "=v"(dst) : "v"(p))
#define AWAIT() do { asm volatile("s_waitcnt vmcnt(0)" ::: "memory"); __builtin_amdgcn_sched_barrier(0); } while(0)

__device__ __forceinline__ float sigm(float x){ return 1.f/(1.f+expf(-x)); }
__device__ __forceinline__ void astoref(float* p, float v){
  __hip_atomic_store(p, v, __ATOMIC_RELAXED, __HIP_MEMORY_SCOPE_AGENT);
}
__device__ __forceinline__ void astoreu64(u64* p, u64 v){
  __hip_atomic_store(p, v, __ATOMIC_RELAXED, __HIP_MEMORY_SCOPE_AGENT);
}
__device__ __forceinline__ u64 aloadu64(const u64* p){
  return __hip_atomic_load((u64*)p, __ATOMIC_RELAXED, __HIP_MEMORY_SCOPE_AGENT);
}

// pack (score, slot) so that u64 max == (max value, min slot on ties) — matches lax.top_k
__device__ __forceinline__ u64 packsc(float v, int slot){
  uint u = __float_as_uint(v);
  u = (u & 0x80000000u) ? ~u : (u | 0x80000000u);
  return ((u64)u << 10) | (u64)(1023 - slot);
}
__device__ __forceinline__ float unpackval(u64 p){
  uint u = (uint)(p >> 10);
  uint bits = (u & 0x80000000u) ? (u & 0x7fffffffu) : ~u;
  return __uint_as_float(bits);
}
__device__ __forceinline__ int unpackslot(u64 p){ return 1023 - (int)(p & 1023u); }

// grid barrier: per-WG arrival flags (128B apart), relaxed agent atomics, no fences, no RMW.
// Safe because: each wave's __syncthreads drains vmcnt(0) (stores acked at coherence point for
// sc0/sc1 write-through stores) before thread0 raises the flag. Flags zeroed by host memset per launch.
__device__ __forceinline__ void gbar(uint* arrv, uint& ls){
  asm volatile("s_waitcnt vmcnt(0)" ::: "memory");   // cover asm-issued stores (untracked)
  __syncthreads();
  ls++;
  if (threadIdx.x == 0)
    __hip_atomic_store(arrv + (size_t)blockIdx.x*32, ls, __ATOMIC_RELAXED, __HIP_MEMORY_SCOPE_AGENT);
  if (threadIdx.x < NWG){
    while (__hip_atomic_load(arrv + (size_t)threadIdx.x*32, __ATOMIC_RELAXED, __HIP_MEMORY_SCOPE_AGENT) < ls)
      __builtin_amdgcn_s_sleep(1);
  }
  __syncthreads();
}

// ---------------- phase 0a: embedding gather ----------------
__global__ __launch_bounds__(256) void prep_emb(const float* __restrict__ E,
                                                const int* __restrict__ seq,
                                                float* __restrict__ EMB){
  int m = blockIdx.x;              // m = t*16 + b
  int t = m >> 4, b = m & 15;
  int x = seq[b*T_STEPS + t];
  EMB[(size_t)m*256 + threadIdx.x] = E[(size_t)x*256 + threadIdx.x];
}

// ---------------- phase 0b: G_emb[m][p] = EMB[m] . W_ih[r(p)][0:256] + b_ih[r]+b_hh[r] ----
// p packing: p = u*4+g, r = g*512+u
__global__ __launch_bounds__(256) void gemm_emb(const float* __restrict__ A,
                                                const float* __restrict__ W_ih,
                                                const float* __restrict__ b_ih,
                                                const float* __restrict__ b_hh,
                                                float* __restrict__ C){
  __shared__ __align__(16) float As[16*68];
  __shared__ __align__(16) float Bs[16*68];
  int mt = blockIdx.x & 31, nt = blockIdx.x >> 5;
  int m0 = mt*64, n0 = nt*64;
  int tx = threadIdx.x & 15, ty = threadIdx.x >> 4;
  float acc[4][4] = {};
  for (int k0 = 0; k0 < 256; k0 += 16){
    int mm = threadIdx.x >> 2, kq = (threadIdx.x & 3)*4;
    float4 a = *(const float4*)(A + (size_t)(m0+mm)*256 + k0 + kq);
    As[(kq+0)*68+mm]=a.x; As[(kq+1)*68+mm]=a.y; As[(kq+2)*68+mm]=a.z; As[(kq+3)*68+mm]=a.w;
    int pp = n0 + mm;
    int r = (pp & 3)*512 + (pp >> 2);
    float4 bv = *(const float4*)(W_ih + (size_t)r*320 + k0 + kq);
    Bs[(kq+0)*68+mm]=bv.x; Bs[(kq+1)*68+mm]=bv.y; Bs[(kq+2)*68+mm]=bv.z; Bs[(kq+3)*68+mm]=bv.w;
    __syncthreads();
    #pragma unroll
    for (int kk = 0; kk < 16; ++kk){
      float4 av = *(const float4*)(As + kk*68 + ty*4);
      float4 bb = *(const float4*)(Bs + kk*68 + tx*4);
      float aa[4] = {av.x,av.y,av.z,av.w};
      float bv2[4] = {bb.x,bb.y,bb.z,bb.w};
      #pragma unroll
      for (int i = 0; i < 4; ++i)
        #pragma unroll
        for (int j = 0; j < 4; ++j)
          acc[i][j] = fmaf(aa[i], bv2[j], acc[i][j]);
    }
    __syncthreads();
  }
  #pragma unroll
  for (int i = 0; i < 4; ++i){
    int m = m0 + ty*4 + i;
    #pragma unroll
    for (int j = 0; j < 4; ++j){
      int pp = n0 + tx*4 + j;
      int r = (pp & 3)*512 + (pp >> 2);
      C[(size_t)m*2048 + pp] = acc[i][j] + b_ih[r] + b_hh[r];
    }
  }
}

// ---------------- the sequential recurrence ----------------
__global__ __launch_bounds__(256, 1) void recurrent_kernel(
    const float* __restrict__ W_hh, const float* __restrict__ W_ih,
    const float* __restrict__ W_rk, const float* __restrict__ b_rk,
    const float* __restrict__ W_wk, const float* __restrict__ b_wk,
    const float* __restrict__ W_wv, const float* __restrict__ b_wv,
    const float* __restrict__ W_er, const float* __restrict__ b_er,
    const float* __restrict__ G_emb, float* __restrict__ H_all,
    float* __restrict__ mem_g, float* __restrict__ projbuf,
    float* __restrict__ rv_g, u64* __restrict__ cand,
    u64* __restrict__ wlist, uint* __restrict__ arrv)
{
  __shared__ __align__(16) float smem[SMEM_F];
  const int tid = threadIdx.x;
  const int wg  = blockIdx.x;
  uint ls = 0;
  float c_reg = 0.f;

  const int p1_b = tid >> 4, p1_col = tid & 15;
  const int pcol = wg*16 + p1_col;                 // packed gate index
  const int rrow = (pcol & 3)*512 + (pcol >> 2);   // original W row

  // ---- P2 constants: stage this WG's projection weight block once (persistent LDS) ----
  const int msel = wg >> 5;
  const int col0 = (wg & 31)*8;
  const float* Wm = (msel==0)? W_rk : (msel==1)? W_wk : (msel==2)? W_wv : W_er;
  const float* bm = (msel==0)? b_rk : (msel==1)? b_wk : (msel==2)? b_wv : b_er;
  {
    float* Ws = smem + OFF_WS;
    for (int i = tid; i < 8*HID; i += 256){
      int k = i >> 3, j = i & 7;
      Ws[j*WROW + k] = Wm[(size_t)k*256 + col0 + j];
    }
  }
  // P3 constants
  const int bb3 = wg >> 3, rg = wg & 7, s0 = rg*128;
  float* mslice_g = mem_g + ((size_t)bb3*NSLOT + s0)*MD;

  #pragma clang loop unroll(disable)
  for (int t = 0; t < T_STEPS; ++t){
    // ======== P1: gates + LSTM (WG owns units wg*4..wg*4+3) ========
    {
      float* xs = smem + OFF_SCR;            // [16][XROW]
      float* gl = smem + OFF_SCR + 9280;     // [16][16]
      if (t > 0){
        const float4* hsrc = (const float4*)(H_all + (size_t)(t-1)*BQ*HID);
        for (int i = tid; i < BQ*HID/4; i += 256){   // normal loads: address written once, never stale
          int b = i >> 7, q = i & 127;
          *(float4*)(xs + b*XROW + q*4) = hsrc[i];
        }
        {
          int b = tid >> 4, dq = tid & 15;
          float4 rvv;
          AL4(rvv, (const float4*)(rv_g + (size_t)b*MD) + dq);
          AWAIT();
          *(float4*)(xs + b*XROW + 512 + dq*4) = rvv;
        }
      } else {
        for (int i = tid; i < BQ*XROW; i += 256) xs[i] = 0.f;
      }
      __syncthreads();
      {
        float a0 = G_emb[(size_t)(t*BQ + p1_b)*2048 + pcol];
        float a1 = 0.f, a2 = 0.f, a3 = 0.f;
        const float4* wh = (const float4*)(W_hh + (size_t)rrow*HID);
        const float4* xv = (const float4*)(xs + p1_b*XROW);
        #pragma unroll 2
        for (int k = 0; k < 128; k += 4){
          float4 w, x;
          w=wh[k+0]; x=xv[k+0]; a0=fmaf(w.x,x.x,a0); a0=fmaf(w.y,x.y,a0); a0=fmaf(w.z,x.z,a0); a0=fmaf(w.w,x.w,a0);
          w=wh[k+1]; x=xv[k+1]; a1=fmaf(w.x,x.x,a1); a1=fmaf(w.y,x.y,a1); a1=fmaf(w.z,x.z,a1); a1=fmaf(w.w,x.w,a1);
          w=wh[k+2]; x=xv[k+2]; a2=fmaf(w.x,x.x,a2); a2=fmaf(w.y,x.y,a2); a2=fmaf(w.z,x.z,a2); a2=fmaf(w.w,x.w,a2);
          w=wh[k+3]; x=xv[k+3]; a3=fmaf(w.x,x.x,a3); a3=fmaf(w.y,x.y,a3); a3=fmaf(w.z,x.z,a3); a3=fmaf(w.w,x.w,a3);
        }
        const float4* wi = (const float4*)(W_ih + (size_t)rrow*320 + 256);
        const float4* xr = (const float4*)(xs + p1_b*XROW + 512);
        #pragma unroll
        for (int k = 0; k < 16; k += 4){
          float4 w, x;
          w=wi[k+0]; x=xr[k+0]; a0=fmaf(w.x,x.x,a0); a0=fmaf(w.y,x.y,a0); a0=fmaf(w.z,x.z,a0); a0=fmaf(w.w,x.w,a0);
          w=wi[k+1]; x=xr[k+1]; a1=fmaf(w.x,x.x,a1); a1=fmaf(w.y,x.y,a1); a1=fmaf(w.z,x.z,a1); a1=fmaf(w.w,x.w,a1);
          w=wi[k+2]; x=xr[k+2]; a2=fmaf(w.x,x.x,a2); a2=fmaf(w.y,x.y,a2); a2=fmaf(w.z,x.z,a2); a2=fmaf(w.w,x.w,a2);
          w=wi[k+3]; x=xr[k+3]; a3=fmaf(w.x,x.x,a3); a3=fmaf(w.y,x.y,a3); a3=fmaf(w.z,x.z,a3); a3=fmaf(w.w,x.w,a3);
        }
        gl[p1_b*16 + p1_col] = (a0+a1)+(a2+a3);
      }
      __syncthreads();
      if (p1_col < 4){
        float gi = gl[p1_b*16 + p1_col*4 + 0];
        float gf = gl[p1_b*16 + p1_col*4 + 1];
        float gg = gl[p1_b*16 + p1_col*4 + 2];
        float go = gl[p1_b*16 + p1_col*4 + 3];
        c_reg = sigm(gf)*c_reg + sigm(gi)*tanhf(gg);
        float h = sigm(go)*tanhf(c_reg);
        astoref(H_all + (size_t)(t*BQ + p1_b)*HID + wg*4 + p1_col, h);
      }
    }
    gbar(arrv, ls);   // B1: h_t visible

    // ======== P2: projections rk|wk|wv|er (WG owns 8 output dims) ========
    {
      float* hs = smem + OFF_SCR;           // [16][WROW]
      float* Ws = smem + OFF_WS;
      const float4* hsrc = (const float4*)(H_all + (size_t)t*BQ*HID);
      for (int i = tid; i < BQ*HID/4; i += 256){
        int b = i >> 7, q = i & 127;
        *(float4*)(hs + b*WROW + q*4) = hsrc[i];
      }
      __syncthreads();
      int b = tid >> 4, o2 = (tid & 15) >> 1, half = tid & 1;
      const float4* wp = (const float4*)(Ws + o2*WROW + half*256);
      const float4* xp = (const float4*)(hs + b*WROW + half*256);
      float a0 = 0.f, a1 = 0.f;
      #pragma unroll 4
      for (int k = 0; k < 64; k += 2){
        float4 w = wp[k], x = xp[k];
        a0=fmaf(w.x,x.x,a0); a0=fmaf(w.y,x.y,a0); a0=fmaf(w.z,x.z,a0); a0=fmaf(w.w,x.w,a0);
        w = wp[k+1]; x = xp[k+1];
        a1=fmaf(w.x,x.x,a1); a1=fmaf(w.y,x.y,a1); a1=fmaf(w.z,x.z,a1); a1=fmaf(w.w,x.w,a1);
      }
      float acc = a0 + a1;
      float other = __shfl_xor(acc, 1);
      if (half == 0){
        float v = acc + other + bm[col0 + o2];
        if (msel == 3) v = sigm(v);
        astoref(projbuf + (size_t)(t&1)*BQ*1024 + (size_t)b*1024 + msel*256 + col0 + o2, v);
      }
    }
    gbar(arrv, ls);   // B2: keys + er/wv visible

    // ======== P3: deferred mem update (LDS-persistent slice) + norms + scores + local top8 ========
    {
      float* mem_s  = smem;                 // persistent [128][68]
      float* nrm_s  = smem + OFF_NRM;       // persistent [128]
      float* scr    = smem + OFF_SCR;
      u64*   wl_s   = (u64*)scr;            // 32 u64
      float* key_s  = scr + 64;             // 512
      float* er_s   = scr + 576;            // 256
      float* wv_s   = scr + 832;            // 256
      float* knrm_s = scr + 1088;           // 8
      float* sc_s   = scr + 1096;           // [8][128]
      const int par = t & 1, parp = par ^ 1;
      const float* projb = projbuf + (size_t)par*BQ*1024 + (size_t)bb3*1024;
      const float* projp = projbuf + (size_t)parp*BQ*1024 + (size_t)bb3*1024;

      if (tid >= 128){                       // waves 2,3: stage this step's 8 keys (rk+wk)
        int i = tid - 128;
        float4 kv;
        AL4(kv, (const float4*)projb + i);
        AWAIT();
        *(float4*)(key_s + i*4) = kv;
      } else if (t == 0){                    // waves 0,1: init slice + global mirror
        for (int i = tid; i < 128*MD; i += 128){
          int row = i >> 6, d = i & 63;
          mem_s[row*68 + d] = 1e-6f;
          astoref(mslice_g + i, 1e-6f);
        }
      } else {                               // waves 0,1: stage write-list + er/wv of prev step
        if (tid < 32)
          wl_s[tid] = aloadu64(wlist + (size_t)bb3*32 + tid);
        if (tid < 64){
          float4 v; AL4(v, (const float4*)(projp + 512) + tid); AWAIT();
          *(float4*)(wv_s + tid*4) = v;
        } else {
          int i = tid - 64;
          float4 v; AL4(v, (const float4*)(projp + 768) + i); AWAIT();
          *(float4*)(er_s + i*4) = v;
        }
      }
      __syncthreads();
      if (t > 0 && tid < 64){
        const int d = tid;
        #pragma unroll 1
        for (int e = 0; e < 32; ++e){        // all erases first (keep = prod over heads)
          u64 w64 = wl_s[e];
          int sl = (int)(w64 & 0xffffffffu);
          if (sl >= s0 && sl < s0+128){
            float w = __uint_as_float((uint)(w64 >> 32));
            int h = e >> 3;
            mem_s[(sl-s0)*68 + d] *= (1.f - w*er_s[h*64 + d]);
          }
        }
        #pragma unroll 1
        for (int e = 0; e < 32; ++e){        // then all adds
          u64 w64 = wl_s[e];
          int sl = (int)(w64 & 0xffffffffu);
          if (sl >= s0 && sl < s0+128){
            float w = __uint_as_float((uint)(w64 >> 32));
            int h = e >> 3;
            mem_s[(sl-s0)*68 + d] += w*wv_s[h*64 + d];
          }
        }
        #pragma unroll 1
        for (int e = 0; e < 32; ++e){        // mirror changed rows to global (for P4's gather)
          u64 w64 = wl_s[e];
          int sl = (int)(w64 & 0xffffffffu);
          if (sl >= s0 && sl < s0+128)
            astoref(mslice_g + (sl-s0)*MD + d, mem_s[(sl-s0)*68 + d]);
        }
      }
      __syncthreads();
      {
        int s = tid >> 1, half = tid & 1;
        const float4* mp = (const float4*)(mem_s + s*68 + half*32);
        float sum = 0.f;
        #pragma unroll
        for (int q = 0; q < 8; ++q){
          float4 v = mp[q];
          sum = fmaf(v.x,v.x,sum); sum = fmaf(v.y,v.y,sum);
          sum = fmaf(v.z,v.z,sum); sum = fmaf(v.w,v.w,sum);
        }
        sum += __shfl_xor(sum, 1);
        if (half == 0) nrm_s[s] = sqrtf(sum) + EPSN;
      }
      if (tid < 8){
        const float4* kp = (const float4*)(key_s + tid*MD);
        float sum = 0.f;
        #pragma unroll
        for (int q = 0; q < 16; ++q){
          float4 v = kp[q];
          sum = fmaf(v.x,v.x,sum); sum = fmaf(v.y,v.y,sum);
          sum = fmaf(v.z,v.z,sum); sum = fmaf(v.w,v.w,sum);
        }
        knrm_s[tid] = sqrtf(sum) + EPSN;
      }
      __syncthreads();
      {
        int s = tid >> 1, kh = tid & 1;
        const float4* mp = (const float4*)(mem_s + s*68);
        float rnm = 1.f / nrm_s[s];
        float acc4[4] = {0.f,0.f,0.f,0.f};
        #pragma unroll
        for (int q = 0; q < 16; ++q){
          float4 m = mp[q];
          #pragma unroll
          for (int kk = 0; kk < 4; ++kk){
            float4 k4 = *(const float4*)(key_s + (kh*4+kk)*MD + q*4);
            acc4[kk] = fmaf(m.x,k4.x,acc4[kk]); acc4[kk] = fmaf(m.y,k4.y,acc4[kk]);
            acc4[kk] = fmaf(m.z,k4.z,acc4[kk]); acc4[kk] = fmaf(m.w,k4.w,acc4[kk]);
          }
        }
        #pragma unroll
        for (int kk = 0; kk < 4; ++kk){
          int key = kh*4 + kk;
          sc_s[key*128 + s] = BETA * acc4[kk] * rnm / knrm_s[key];
        }
      }
      __syncthreads();
      {
        int wid = tid >> 6, lane = tid & 63;
        #pragma unroll
        for (int kk = 0; kk < 2; ++kk){
          int key = wid*2 + kk;
          u64 p0 = packsc(sc_s[key*128 + lane],      s0 + lane);
          u64 p1 = packsc(sc_s[key*128 + 64 + lane], s0 + 64 + lane);
          #pragma unroll
          for (int r = 0; r < 8; ++r){
            u64 m = p0 > p1 ? p0 : p1;
            #pragma unroll
            for (int o = 32; o; o >>= 1){ u64 q = __shfl_xor(m, o); if (q > m) m = q; }
            if (p0 == m) p0 = 0; else if (p1 == m) p1 = 0;
            if (lane == 0) astoreu64(cand + (((size_t)bb3*8 + key)*8 + rg)*8 + r, m);
          }
        }
      }
    }
    gbar(arrv, ls);   // B3: candidates + mirrored mem rows visible

    // ======== P4: merge top8, softmax, read_vec, write-lists (one WG per b) ========
    if (wg < BQ){
      const int bb = wg;
      float* rvp = smem + OFF_SCR;   // [4][64]
      int wid = tid >> 6, lane = tid & 63;
      #pragma unroll
      for (int kk = 0; kk < 2; ++kk){
        int key = wid*2 + kk;
        u64 pv = aloadu64(cand + (((size_t)bb*8 + key)*8 + (lane >> 3))*8 + (lane & 7));
        u64 sel = 0;
        #pragma unroll
        for (int r = 0; r < 8; ++r){
          u64 m = pv;
          #pragma unroll
          for (int o = 32; o; o >>= 1){ u64 q = __shfl_xor(m, o); if (q > m) m = q; }
          if (pv == m) pv = 0;
          if (lane == r) sel = m;
        }
        float val = unpackval(sel);
        int slot = unpackslot(sel);
        float vmax = __shfl(val, 0);
        float e = (lane < 8) ? expf(val - vmax) : 0.f;
        float ssum = e;
        #pragma unroll
        for (int o = 32; o; o >>= 1) ssum += __shfl_xor(ssum, o);
        float w = e / ssum;
        if (key < 4){
          int sls[8];
          #pragma unroll
          for (int i = 0; i < 8; ++i) sls[i] = __shfl(slot, i);
          float mv[8];
          #pragma unroll
          for (int i = 0; i < 8; ++i)
            ALF(mv[i], mem_g + ((size_t)bb*NSLOT + sls[i])*MD + lane);
          AWAIT();
          float acc = 0.f;
          #pragma unroll
          for (int i = 0; i < 8; ++i) acc = fmaf(__shfl(w, i), mv[i], acc);
          rvp[key*64 + lane] = acc;
        } else if (lane < 8){
          astoreu64(wlist + (size_t)bb*32 + (key-4)*8 + lane,
                    ((u64)__float_as_uint(w) << 32) | (u64)(uint)slot);
        }
      }
      __syncthreads();
      if (tid < 64){
        float m = 0.25f*(rvp[tid] + rvp[64+tid] + rvp[128+tid] + rvp[192+tid]);
        astoref(rv_g + (size_t)bb*MD + tid, m);
      }
    }
    gbar(arrv, ls);   // B4: rv + write lists visible
  }
}

// ---------------- phase B: logits = H_all[2048,512] @ W_out[512,32000] + b_out ----------------
__global__ __launch_bounds__(256) void gemm_out(const float* __restrict__ A,
                                                const float* __restrict__ Bmat,
                                                const float* __restrict__ bias,
                                                float* __restrict__ C){
  __shared__ __align__(16) float As[16*132];
  __shared__ __align__(16) float Bs[16*64];
  int mt = blockIdx.x & 15, nt = blockIdx.x >> 4;
  int m0 = mt*128, n0 = nt*64;
  int tx = threadIdx.x & 15, ty = threadIdx.x >> 4;
  float acc[8][4] = {};
  for (int k0 = 0; k0 < 512; k0 += 16){
    int mm = threadIdx.x >> 1, kq = (threadIdx.x & 1)*8;
    float4 a0 = *(const float4*)(A + (size_t)(m0+mm)*512 + k0 + kq);
    float4 a1 = *(const float4*)(A + (size_t)(m0+mm)*512 + k0 + kq + 4);
    As[(kq+0)*132+mm]=a0.x; As[(kq+1)*132+mm]=a0.y; As[(kq+2)*132+mm]=a0.z; As[(kq+3)*132+mm]=a0.w;
    As[(kq+4)*132+mm]=a1.x; As[(kq+5)*132+mm]=a1.y; As[(kq+6)*132+mm]=a1.z; As[(kq+7)*132+mm]=a1.w;
    int kk2 = threadIdx.x >> 4, nq = (threadIdx.x & 15)*4;
    *(float4*)(Bs + kk2*64 + nq) = *(const float4*)(Bmat + (size_t)(k0+kk2)*VOCAB + n0 + nq);
    __syncthreads();
    #pragma unroll
    for (int kk = 0; kk < 16; ++kk){
      float4 x0 = *(const float4*)(As + kk*132 + ty*8);
      float4 x1 = *(const float4*)(As + kk*132 + ty*8 + 4);
      float4 bv = *(const float4*)(Bs + kk*64 + tx*4);
      float aa[8] = {x0.x,x0.y,x0.z,x0.w,x1.x,x1.y,x1.z,x1.w};
      float bb[4] = {bv.x,bv.y,bv.z,bv.w};
      #pragma unroll
      for (int i = 0; i < 8; ++i)
        #pragma unroll
        for (int j = 0; j < 4; ++j)
          acc[i][j] = fmaf(aa[i], bb[j], acc[i][j]);
    }
    __syncthreads();
  }
  #pragma unroll
  for (int i = 0; i < 8; ++i){
    int m = m0 + ty*8 + i;
    int bq = m & 15, tt = m >> 4;
    float* crow = C + ((size_t)bq*T_STEPS + tt)*VOCAB + n0 + tx*4;
    #pragma unroll
    for (int j = 0; j < 4; ++j) crow[j] = acc[i][j] + bias[n0 + tx*4 + j];
  }
}

extern "C" void kernel_launch(void* const* d_in, const int* in_sizes, int n_in,
                              void* d_out, int out_size, void* d_ws, size_t ws_size,
                              hipStream_t stream){
  const int*   seq   = (const int*)d_in[0];
  const float* E     = (const float*)d_in[1];
  const float* W_ih  = (const float*)d_in[2];
  const float* W_hh  = (const float*)d_in[3];
  const float* b_ih  = (const float*)d_in[4];
  const float* b_hh  = (const float*)d_in[5];
  const float* W_out = (const float*)d_in[6];
  const float* b_out = (const float*)d_in[7];
  const float* W_rk  = (const float*)d_in[8];
  const float* b_rk  = (const float*)d_in[9];
  const float* W_wk  = (const float*)d_in[10];
  const float* b_wk  = (const float*)d_in[11];
  const float* W_wv  = (const float*)d_in[12];
  const float* b_wv  = (const float*)d_in[13];
  const float* W_er  = (const float*)d_in[14];
  const float* b_er  = (const float*)d_in[15];
  float* out = (float*)d_out;
  (void)in_sizes; (void)n_in; (void)out_size; (void)ws_size;

  char* ws = (char*)d_ws;
  size_t off = 0;
  auto alloc = [&](size_t bytes) -> void* {
    off = (off + 255) & ~(size_t)255;
    void* p = ws + off;
    off += bytes;
    return p;
  };
  float* EMB     = (float*)alloc((size_t)2048*256*4);
  float* G_emb   = (float*)alloc((size_t)2048*2048*4);
  float* H_all   = (float*)alloc((size_t)2048*512*4);
  float* memb    = (float*)alloc((size_t)16*1024*64*4);
  float* projbuf = (float*)alloc((size_t)2*16*1024*4);
  float* rv_g    = (float*)alloc((size_t)16*64*4);
  u64*   cand    = (u64*)alloc((size_t)16*8*8*8*8);
  u64*   wlist   = (u64*)alloc((size_t)16*32*8);
  uint*  arrv    = (uint*)alloc((size_t)NWG*32*4);

  hipMemsetAsync(arrv, 0, (size_t)NWG*32*4, stream);   // flags must be zero each replay
  prep_emb<<<2048, 256, 0, stream>>>(E, seq, EMB);
  gemm_emb<<<1024, 256, 0, stream>>>(EMB, W_ih, b_ih, b_hh, G_emb);
  recurrent_kernel<<<NWG, 256, 0, stream>>>(W_hh, W_ih, W_rk, b_rk, W_wk, b_wk,
                                            W_wv, b_wv, W_er, b_er,
                                            G_emb, H_all, memb, projbuf, rv_g,
                                            cand, wlist, arrv);
  gemm_out<<<16*500, 256, 0, stream>>>(H_all, W_out, b_out, out);
}